// Round 7
// baseline (330.652 us; speedup 1.0000x reference)
//
#include <hip/hip_runtime.h>
#include <math.h>

// BVP Helmholtz-residual PINN via MFMA, round 7.
// psi = MLP(4 -> 256 -> 256 -> 256 -> 2), tanh. Jet: 7 streams per point =
// 7 GEMM cols; PBLK=32 points/block, col = s*32 + p, ct = 2s + (p>>4)
// (even col-tiles = points 0..15, odd = 16..31).
// Round-6 lesson: B-panel LDS traffic = 7*W KB/point — TLP inflates the
// dominant pipe (LDS ~50% busy). Round 7: 8 waves x (64 rows x 112 cols)
// tiles (4rt x 7ct = 28 MFMA/kc): halves LDS bytes/point, 28-MFMA issue
// (~129 cyc) self-covers next kc's ds_read latency. 117 KB dynamic LDS,
// 1 block/CU. Same lane-local jet via k-permutation (W3 cols permuted).

typedef __attribute__((ext_vector_type(8))) short short8;
typedef __attribute__((ext_vector_type(4))) float floatx4;
typedef unsigned short ushort_t;
typedef unsigned int uint_t;

#define PBLK 32
#define LDS_BYTES (114688 + 4096)

__device__ __forceinline__ ushort_t f2bf(float f) {
    uint_t u = __float_as_uint(f);
    return (ushort_t)((u + 0x7FFFu + ((u >> 16) & 1u)) >> 16);  // RNE
}
// pack2bf(f0,f1): {bf16(f0), bf16(f1)} in one u32 (f0 low). Round-half-up.
__device__ __forceinline__ uint_t pack2bf(float f0, float f1) {
    uint_t u0 = __float_as_uint(f0) + 0x8000u;
    uint_t u1 = __float_as_uint(f1) + 0x8000u;
    return __builtin_amdgcn_perm(u1, u0, 0x07060302u);
}
__device__ __forceinline__ float fast_tanh(float u) {
    float e = __expf(2.f * u);
    return 1.f - 2.f / (e + 1.f);   // exact at +-inf for finite u
}

// ws: 2 layers x 16 row-tiles x 8 kc x 64 lanes x 16B = 256 KB.
// A-frag lane (m=lane&15, qa=lane>>4) slot j:
//   layer0 (W2, natural):  col = kc*32 + 8*qa + j
//   layer1 (W3, permuted): col = kc*32 + 16*(j>>2) + 4*qa + (j&3)
__global__ void prep_split(const float* __restrict__ W2, const float* __restrict__ W3,
                           short8* __restrict__ ws) {
    int t16 = blockIdx.x * blockDim.x + threadIdx.x;  // 0..16383
    int lane = t16 & 63;
    int kc = (t16 >> 6) & 7;
    int tt = (t16 >> 9) & 15;
    int l = t16 >> 13;
    const float* W = l ? W3 : W2;
    int row = tt * 16 + (lane & 15);
    int qa = lane >> 4;
    const float* src = W + row * 256 + kc * 32 + (l ? 4 * qa : 8 * qa);
    float4 va = *(const float4*)src;
    float4 vb = *(const float4*)(src + (l ? 16 : 4));
    float v[8] = {va.x, va.y, va.z, va.w, vb.x, vb.y, vb.z, vb.w};
    short8 hi8;
    #pragma unroll
    for (int j = 0; j < 8; ++j) hi8[j] = (short)f2bf(v[j]);   // RNE (runs once)
    ws[l * 8192 + tt * 512 + kc * 64 + lane] = hi8;
}

__global__ __launch_bounds__(512, 2)
void bvp_main(const float* __restrict__ gx, const float* __restrict__ gy,
              const float* __restrict__ gz, const float* __restrict__ gf,
              const float* __restrict__ W1, const float* __restrict__ b1,
              const float* __restrict__ b2, const float* __restrict__ b3,
              const float* __restrict__ W4, const float* __restrict__ b4,
              const short8* __restrict__ wsA, float* __restrict__ out, int N) {
    extern __shared__ char smem[];
    short8* const Bsh = (short8*)smem;             // [ct(14)][kc(8)][lane(64)]
    float* const red = (float*)(smem + 114688);    // [R(4)][p(32)][8]

    const int tid = threadIdx.x;
    const int w = tid >> 6, lane = tid & 63;
    const int n15 = lane & 15, qc = lane >> 4;
    const int g = w & 1, R = w >> 1;               // col-group (point half), row-group
    const int pbase = blockIdx.x * PBLK;
    const short8* __restrict__ wsA3 = wsA + 8192;

    floatx4 acc[4][7];   // 4 row-tiles (64 rows) x 7 local col-tiles
    short8 a0[4], a1[4];

    // GEMM-2 A(kc=0): issue now, covered by layer-1 math.
    #pragma unroll
    for (int rt = 0; rt < 4; ++rt) a0[rt] = wsA[(R * 4 + rt) * 512 + lane];

    // ---------------- layer 1 (VALU) -> B fragments ----------------
    // thread (pp = tid&31, u8 = tid>>5) does neurons u8*16..+15 for point pp.
    {
        const int pp = tid & 31, u8 = tid >> 5;
        const int pidx = min(pbase + pp, N - 1);
        const float xi = gx[pidx], yi = gy[pidx], zi = gz[pidx], fi = gf[pidx];
        const int kc = u8 >> 1, cthi = pp >> 4, ppl = pp & 15;
        #pragma unroll
        for (int g2 = 0; g2 < 2; ++g2) {
            float hv[7][8];
            #pragma unroll
            for (int r = 0; r < 8; ++r) {
                const int i = u8 * 16 + g2 * 8 + r;
                float4 wv = *(const float4*)(W1 + 4 * i);
                float u = fmaf(wv.x, xi, fmaf(wv.y, yi, fmaf(wv.z, zi, fmaf(wv.w, fi, b1[i]))));
                float t = fast_tanh(u), s = 1.f - t * t, c = -2.f * t * s;
                hv[0][r] = t;
                hv[1][r] = s * wv.x; hv[2][r] = s * wv.y; hv[3][r] = s * wv.z;
                hv[4][r] = c * wv.x * wv.x; hv[5][r] = c * wv.y * wv.y; hv[6][r] = c * wv.z * wv.z;
            }
            const int q = (u8 & 1) * 2 + g2;           // k-slot q (natural order)
            const int ln = q * 16 + ppl;
            #pragma unroll
            for (int s = 0; s < 7; ++s) {
                union { short8 s8; uint_t u4[4]; } v;
                #pragma unroll
                for (int j = 0; j < 4; ++j)
                    v.u4[j] = pack2bf(hv[s][2 * j], hv[s][2 * j + 1]);
                Bsh[((2 * s + cthi) * 8 + kc) * 64 + ln] = v.s8;
            }
        }
    }
    __syncthreads();

    // K-loop: A 1-deep global prefetch (L2-resident); 28 MFMA/kc (~129 cyc
    // issue) covers the next kc's 7 ds_read_b128.
    auto run_gemm = [&](const short8* __restrict__ A) {
        #pragma unroll
        for (int rt = 0; rt < 4; ++rt)
            #pragma unroll
            for (int ct = 0; ct < 7; ++ct) acc[rt][ct] = (floatx4){0.f, 0.f, 0.f, 0.f};
        #pragma unroll
        for (int kc = 0; kc < 8; ++kc) {
            if (kc < 7) {
                #pragma unroll
                for (int rt = 0; rt < 4; ++rt)
                    a1[rt] = A[(R * 4 + rt) * 512 + (kc + 1) * 64 + lane];
            }
            short8 b[7];
            #pragma unroll
            for (int ct = 0; ct < 7; ++ct) b[ct] = Bsh[((2 * ct + g) * 8 + kc) * 64 + lane];
            #pragma unroll
            for (int ct = 0; ct < 7; ++ct)
                #pragma unroll
                for (int rt = 0; rt < 4; ++rt)
                    acc[rt][ct] = __builtin_amdgcn_mfma_f32_16x16x32_bf16(a0[rt], b[ct], acc[rt][ct], 0, 0, 0);
            if (kc < 7) {
                #pragma unroll
                for (int rt = 0; rt < 4; ++rt) a0[rt] = a1[rt];
            }
        }
    };

    // ---------------- GEMM 2 ----------------
    run_gemm(wsA);
    __syncthreads();   // all waves done reading layer-2 B

    // GEMM-3 A(kc=0): issue now, covered by jet-2 math.
    #pragma unroll
    for (int rt = 0; rt < 4; ++rt) a0[rt] = wsA3[(R * 4 + rt) * 512 + lane];

    // ---------------- jet 2 (lane-local) -> new B fragments ----------------
    // acc[rt][s] holds stream s for point g*16+n15, rows R*64+rt*16+qc*4+r.
    #pragma unroll
    for (int rt = 0; rt < 4; ++rt) {
        const float4 bb = *(const float4*)(b2 + R * 64 + rt * 16 + qc * 4);
        const float bbv[4] = {bb.x, bb.y, bb.z, bb.w};
        #pragma unroll
        for (int r = 0; r < 4; ++r) {
            float t = fast_tanh(acc[rt][0][r] + bbv[r]);
            float s = 1.f - t * t, c = -2.f * t * s;
            float ux = acc[rt][1][r], uy = acc[rt][2][r], uz = acc[rt][3][r];
            acc[rt][0][r] = t;
            acc[rt][1][r] = s * ux; acc[rt][2][r] = s * uy; acc[rt][3][r] = s * uz;
            acc[rt][4][r] = fmaf(s, acc[rt][4][r], c * ux * ux);
            acc[rt][5][r] = fmaf(s, acc[rt][5][r], c * uy * uy);
            acc[rt][6][r] = fmaf(s, acc[rt][6][r], c * uz * uz);
        }
    }
    // permuted k-order k(q,j)=kc*32+16*(j>>2)+4q+(j&3): slot j=(rt&1)*4+r,
    // q=qc, kt=2R+hh -> each lane writes its own B-frag slot.
    #pragma unroll
    for (int hh = 0; hh < 2; ++hh)
        #pragma unroll
        for (int s = 0; s < 7; ++s) {
            union { short8 s8; uint_t u4[4]; } v;
            v.u4[0] = pack2bf(acc[2 * hh][s][0], acc[2 * hh][s][1]);
            v.u4[1] = pack2bf(acc[2 * hh][s][2], acc[2 * hh][s][3]);
            v.u4[2] = pack2bf(acc[2 * hh + 1][s][0], acc[2 * hh + 1][s][1]);
            v.u4[3] = pack2bf(acc[2 * hh + 1][s][2], acc[2 * hh + 1][s][3]);
            Bsh[((2 * s + g) * 8 + 2 * R + hh) * 64 + lane] = v.s8;
        }
    __syncthreads();

    // ---------------- GEMM 3 ----------------
    run_gemm(wsA3);

    // ---------------- jet 3 + layer-4 partials (lane-local) ----------------
    float pt[8] = {0.f, 0.f, 0.f, 0.f, 0.f, 0.f, 0.f, 0.f};
    #pragma unroll
    for (int rt = 0; rt < 4; ++rt) {
        const int rb = R * 64 + rt * 16 + qc * 4;
        const float4 bb = *(const float4*)(b3 + rb);
        const float4 w0 = *(const float4*)(W4 + rb);
        const float4 w1 = *(const float4*)(W4 + 256 + rb);
        const float bbv[4] = {bb.x, bb.y, bb.z, bb.w};
        const float w0v[4] = {w0.x, w0.y, w0.z, w0.w};
        const float w1v[4] = {w1.x, w1.y, w1.z, w1.w};
        #pragma unroll
        for (int r = 0; r < 4; ++r) {
            float t = fast_tanh(acc[rt][0][r] + bbv[r]);
            float s = 1.f - t * t, c = -2.f * t * s;
            float ux = acc[rt][1][r], uy = acc[rt][2][r], uz = acc[rt][3][r];
            float hv = t;
            float hxx = fmaf(s, acc[rt][4][r], c * ux * ux);
            float hyy = fmaf(s, acc[rt][5][r], c * uy * uy);
            float hzz = fmaf(s, acc[rt][6][r], c * uz * uz);
            pt[0] = fmaf(w0v[r], hv, pt[0]);
            pt[1] = fmaf(w0v[r], hxx, pt[1]);
            pt[2] = fmaf(w0v[r], hyy, pt[2]);
            pt[3] = fmaf(w0v[r], hzz, pt[3]);
            pt[4] = fmaf(w1v[r], hv, pt[4]);
            pt[5] = fmaf(w1v[r], hxx, pt[5]);
            pt[6] = fmaf(w1v[r], hyy, pt[6]);
            pt[7] = fmaf(w1v[r], hzz, pt[7]);
        }
    }
    #pragma unroll
    for (int k = 0; k < 8; ++k) {
        pt[k] += __shfl_xor(pt[k], 16, 64);
        pt[k] += __shfl_xor(pt[k], 32, 64);
    }
    if (qc == 0) {
        const int p = g * 16 + n15;
        *(float4*)&red[(R * 32 + p) * 8 + 0] = make_float4(pt[0], pt[1], pt[2], pt[3]);
        *(float4*)&red[(R * 32 + p) * 8 + 4] = make_float4(pt[4], pt[5], pt[6], pt[7]);
    }
    __syncthreads();

    if (tid < 32 && (pbase + tid) < N) {
        const int n = pbase + tid;
        float s8[8] = {0.f, 0.f, 0.f, 0.f, 0.f, 0.f, 0.f, 0.f};
        #pragma unroll
        for (int ww = 0; ww < 4; ++ww)
            #pragma unroll
            for (int k = 0; k < 8; ++k) s8[k] += red[(ww * 32 + tid) * 8 + k];
        const float fi = gf[n];
        const float PI = 3.14159265358979323846f;
        const float kw = 2.f * PI * (fi * 500.f + 100.f) / 343.f;
        const float vol = 0.7f * 0.5f * 0.6f;
        const float kk = vol * vol * kw * kw;
        const float cxx = (0.5f * 0.6f) * (0.5f * 0.6f);
        const float cyy = (0.7f * 0.6f) * (0.7f * 0.6f);
        const float czz = (0.7f * 0.5f) * (0.7f * 0.5f);
        const float pr = s8[0] + b4[0];
        const float pim = s8[4] + b4[1];
        out[n]     = 2.0f * (cxx * s8[1] + cyy * s8[2] + czz * s8[3]) + kk * (pr * 2.0f + 0.1f);
        out[N + n] = 1.5f * (cxx * s8[5] + cyy * s8[6] + czz * s8[7]) + kk * (pim * 1.5f - 0.05f);
    }
}

extern "C" void kernel_launch(void* const* d_in, const int* in_sizes, int n_in,
                              void* d_out, int out_size, void* d_ws, size_t ws_size,
                              hipStream_t stream) {
    const float* x = (const float*)d_in[0];
    const float* y = (const float*)d_in[1];
    const float* z = (const float*)d_in[2];
    const float* f = (const float*)d_in[3];
    const float* W1 = (const float*)d_in[4];
    const float* b1 = (const float*)d_in[5];
    const float* W2 = (const float*)d_in[6];
    const float* b2 = (const float*)d_in[7];
    const float* W3 = (const float*)d_in[8];
    const float* b3 = (const float*)d_in[9];
    const float* W4 = (const float*)d_in[10];
    const float* b4 = (const float*)d_in[11];
    float* out = (float*)d_out;
    const int N = in_sizes[0];
    const int grid = (N + PBLK - 1) / PBLK;

    prep_split<<<64, 256, 0, stream>>>(W2, W3, (short8*)d_ws);
    const void* kf = reinterpret_cast<const void*>(&bvp_main);
    (void)hipFuncSetAttribute(kf, hipFuncAttributeMaxDynamicSharedMemorySize, LDS_BYTES);
    bvp_main<<<grid, 512, LDS_BYTES, stream>>>(x, y, z, f, W1, b1, b2, b3, W4, b4,
                                               (const short8*)d_ws, out, N);
}

// Round 8
// 326.372 us; speedup vs baseline: 1.0131x; 1.0131x over previous
//
#include <hip/hip_runtime.h>
#include <math.h>

// BVP Helmholtz-residual PINN via MFMA, round 8.
// psi = MLP(4 -> 256 -> 256 -> 256 -> 2), tanh. Jet: 7 streams per point =
// 7 GEMM cols, col = s*16 + p. Structure = round 6 (best, 257us):
// 512 thr / 8 waves x 32 rows, P=16, 59 KB LDS -> 2 blocks/CU, 4 waves/SIMD,
// A-from-L2 (no K-loop barriers), lane-local jet via k-permutation.
// Round-8 change: STAGGERED K-LOOP — wave w runs kc = w, w+1, ..., w+7
// (mod 8). R7 proved LDS *traffic* isn't binding (halving it at fixed TLP
// was neutral); the 45% wall slack over the 141us LDS floor is barrier
// convoys: all 16 resident waves burst identical ds_reads after each
// __syncthreads, then all sit in MFMA together while LDS idles. Staggering
// spreads waves across 8 kc phases -> LDS pipe streams continuously.
// (fp32 MFMA accumulation is kc-order-independent up to rounding.)

typedef __attribute__((ext_vector_type(8))) short short8;
typedef __attribute__((ext_vector_type(4))) float floatx4;
typedef unsigned short ushort_t;
typedef unsigned int uint_t;

#define PBLK 16

__device__ __forceinline__ ushort_t f2bf(float f) {
    uint_t u = __float_as_uint(f);
    return (ushort_t)((u + 0x7FFFu + ((u >> 16) & 1u)) >> 16);  // RNE
}
// pack2bf(f0,f1): {bf16(f0), bf16(f1)} in one u32 (f0 low). Round-half-up.
__device__ __forceinline__ uint_t pack2bf(float f0, float f1) {
    uint_t u0 = __float_as_uint(f0) + 0x8000u;
    uint_t u1 = __float_as_uint(f1) + 0x8000u;
    return __builtin_amdgcn_perm(u1, u0, 0x07060302u);
}
__device__ __forceinline__ float fast_tanh(float u) {
    float e = __expf(2.f * u);
    return 1.f - 2.f / (e + 1.f);   // exact at +-inf for finite u
}

// ws: 2 layers x 16 row-tiles x 8 kc x 64 lanes x 16B = 256 KB.
// A-frag lane (m=lane&15, qa=lane>>4) slot j:
//   layer0 (W2, natural):  col = kc*32 + 8*qa + j
//   layer1 (W3, permuted): col = kc*32 + 16*(j>>2) + 4*qa + (j&3)
__global__ void prep_split(const float* __restrict__ W2, const float* __restrict__ W3,
                           short8* __restrict__ ws) {
    int t16 = blockIdx.x * blockDim.x + threadIdx.x;  // 0..16383
    int lane = t16 & 63;
    int kc = (t16 >> 6) & 7;
    int tt = (t16 >> 9) & 15;
    int l = t16 >> 13;
    const float* W = l ? W3 : W2;
    int row = tt * 16 + (lane & 15);
    int qa = lane >> 4;
    const float* src = W + row * 256 + kc * 32 + (l ? 4 * qa : 8 * qa);
    float4 va = *(const float4*)src;
    float4 vb = *(const float4*)(src + (l ? 16 : 4));
    float v[8] = {va.x, va.y, va.z, va.w, vb.x, vb.y, vb.z, vb.w};
    short8 hi8;
    #pragma unroll
    for (int j = 0; j < 8; ++j) hi8[j] = (short)f2bf(v[j]);   // RNE (runs once)
    ws[l * 8192 + tt * 512 + kc * 64 + lane] = hi8;
}

__global__ __launch_bounds__(512, 4)
void bvp_main(const float* __restrict__ gx, const float* __restrict__ gy,
              const float* __restrict__ gz, const float* __restrict__ gf,
              const float* __restrict__ W1, const float* __restrict__ b1,
              const float* __restrict__ b2, const float* __restrict__ b3,
              const float* __restrict__ W4, const float* __restrict__ b4,
              const short8* __restrict__ wsA, float* __restrict__ out, int N) {
    __shared__ short8 Bsh[7 * 8 * 64];   // 57344 B: B[s][kt][lane]
    __shared__ float red[8][16][8];      // 4 KB cross-wave reduction scratch

    const int tid = threadIdx.x;
    const int w = tid >> 6, lane = tid & 63;
    const int n15 = lane & 15, qc = lane >> 4;
    const int pbase = blockIdx.x * PBLK;
    const short8* __restrict__ wsA3 = wsA + 8192;
    const int kc0 = w & 7;               // this wave's staggered start phase

    floatx4 acc[2][7];   // 2 row-tiles (32 rows) x 7 streams
    short8 a0[2], a1[2];

    // GEMM-2 A(kc = kc0): issue now, covered by layer-1 math.
    #pragma unroll
    for (int rt = 0; rt < 2; ++rt) a0[rt] = wsA[(2 * w + rt) * 512 + kc0 * 64 + lane];

    // ---------------- layer 1 (VALU) -> B fragments ----------------
    // pp = tid&15: 16-lane groups write contiguous 256B -> conflict-free;
    // threads sharing u8 read the same W1 rows (broadcast).
    {
        const int pp = tid & 15, u8 = tid >> 4;     // u8 in 0..31: neurons 8*u8..+7
        const int pidx = min(pbase + pp, N - 1);
        const float xi = gx[pidx], yi = gy[pidx], zi = gz[pidx], fi = gf[pidx];
        float hv[7][8];
        #pragma unroll
        for (int r = 0; r < 8; ++r) {
            const int i = u8 * 8 + r;
            float4 wv = *(const float4*)(W1 + 4 * i);
            float u = fmaf(wv.x, xi, fmaf(wv.y, yi, fmaf(wv.z, zi, fmaf(wv.w, fi, b1[i]))));
            float t = fast_tanh(u), s = 1.f - t * t, c = -2.f * t * s;
            hv[0][r] = t;
            hv[1][r] = s * wv.x; hv[2][r] = s * wv.y; hv[3][r] = s * wv.z;
            hv[4][r] = c * wv.x * wv.x; hv[5][r] = c * wv.y * wv.y; hv[6][r] = c * wv.z * wv.z;
        }
        const int kt = u8 >> 2, qb = u8 & 3;        // k-slot qb*8+r (natural order)
        #pragma unroll
        for (int s = 0; s < 7; ++s) {
            union { short8 s8; uint_t u4[4]; } v;
            #pragma unroll
            for (int j = 0; j < 4; ++j)
                v.u4[j] = pack2bf(hv[s][2 * j], hv[s][2 * j + 1]);
            Bsh[(s * 8 + kt) * 64 + qb * 16 + pp] = v.s8;
        }
    }
    __syncthreads();

    // Staggered K-loop: wave w sweeps kc = kc0..kc0+7 (mod 8).
    // A 1-deep global prefetch (L2-resident), B single-buffer LDS.
    auto run_gemm = [&](const short8* __restrict__ A) {
        #pragma unroll
        for (int rt = 0; rt < 2; ++rt)
            #pragma unroll
            for (int ct = 0; ct < 7; ++ct) acc[rt][ct] = (floatx4){0.f, 0.f, 0.f, 0.f};
        #pragma unroll
        for (int it = 0; it < 8; ++it) {
            const int kcs = (kc0 + it) & 7;
            if (it < 7) {
                const int kn = (kc0 + it + 1) & 7;
                #pragma unroll
                for (int rt = 0; rt < 2; ++rt)
                    a1[rt] = A[(2 * w + rt) * 512 + kn * 64 + lane];
            }
            short8 b[7];
            #pragma unroll
            for (int ct = 0; ct < 7; ++ct) b[ct] = Bsh[(ct * 8 + kcs) * 64 + lane];
            #pragma unroll
            for (int ct = 0; ct < 7; ++ct)
                #pragma unroll
                for (int rt = 0; rt < 2; ++rt)
                    acc[rt][ct] = __builtin_amdgcn_mfma_f32_16x16x32_bf16(a0[rt], b[ct], acc[rt][ct], 0, 0, 0);
            if (it < 7) {
                #pragma unroll
                for (int rt = 0; rt < 2; ++rt) a0[rt] = a1[rt];
            }
        }
    };

    // ---------------- GEMM 2 ----------------
    run_gemm(wsA);
    __syncthreads();   // all waves done reading layer-2 B

    // GEMM-3 A(kc = kc0): issue now, covered by jet-2 math.
    #pragma unroll
    for (int rt = 0; rt < 2; ++rt) a0[rt] = wsA3[(2 * w + rt) * 512 + kc0 * 64 + lane];

    // ---------------- jet 2 (lane-local) -> new B fragments ----------------
    // Wave w's 32 rows are exactly k-tile w; permuted k-order
    // k(qc,j)=16(j>>2)+4qc+(j&3) makes the repack lane-local.
    #pragma unroll
    for (int rt = 0; rt < 2; ++rt) {
        const float4 bb = *(const float4*)(b2 + w * 32 + rt * 16 + qc * 4);
        const float bbv[4] = {bb.x, bb.y, bb.z, bb.w};
        #pragma unroll
        for (int r = 0; r < 4; ++r) {
            float t = fast_tanh(acc[rt][0][r] + bbv[r]);
            float s = 1.f - t * t, c = -2.f * t * s;
            float ux = acc[rt][1][r], uy = acc[rt][2][r], uz = acc[rt][3][r];
            acc[rt][0][r] = t;
            acc[rt][1][r] = s * ux; acc[rt][2][r] = s * uy; acc[rt][3][r] = s * uz;
            acc[rt][4][r] = fmaf(s, acc[rt][4][r], c * ux * ux);
            acc[rt][5][r] = fmaf(s, acc[rt][5][r], c * uy * uy);
            acc[rt][6][r] = fmaf(s, acc[rt][6][r], c * uz * uz);
        }
    }
    #pragma unroll
    for (int s = 0; s < 7; ++s) {
        union { short8 s8; uint_t u4[4]; } v;
        v.u4[0] = pack2bf(acc[0][s][0], acc[0][s][1]);
        v.u4[1] = pack2bf(acc[0][s][2], acc[0][s][3]);
        v.u4[2] = pack2bf(acc[1][s][0], acc[1][s][1]);
        v.u4[3] = pack2bf(acc[1][s][2], acc[1][s][3]);
        Bsh[(s * 8 + w) * 64 + lane] = v.s8;   // kt = w, own lane slot
    }
    __syncthreads();

    // ---------------- GEMM 3 ----------------
    run_gemm(wsA3);

    // ---------------- jet 3 + layer-4 partials (lane-local) ----------------
    float pt[8] = {0.f, 0.f, 0.f, 0.f, 0.f, 0.f, 0.f, 0.f};
    #pragma unroll
    for (int rt = 0; rt < 2; ++rt) {
        const int rb = w * 32 + rt * 16 + qc * 4;
        const float4 bb = *(const float4*)(b3 + rb);
        const float4 w0 = *(const float4*)(W4 + rb);
        const float4 w1 = *(const float4*)(W4 + 256 + rb);
        const float bbv[4] = {bb.x, bb.y, bb.z, bb.w};
        const float w0v[4] = {w0.x, w0.y, w0.z, w0.w};
        const float w1v[4] = {w1.x, w1.y, w1.z, w1.w};
        #pragma unroll
        for (int r = 0; r < 4; ++r) {
            float t = fast_tanh(acc[rt][0][r] + bbv[r]);
            float s = 1.f - t * t, c = -2.f * t * s;
            float ux = acc[rt][1][r], uy = acc[rt][2][r], uz = acc[rt][3][r];
            float hv = t;
            float hxx = fmaf(s, acc[rt][4][r], c * ux * ux);
            float hyy = fmaf(s, acc[rt][5][r], c * uy * uy);
            float hzz = fmaf(s, acc[rt][6][r], c * uz * uz);
            pt[0] = fmaf(w0v[r], hv, pt[0]);
            pt[1] = fmaf(w0v[r], hxx, pt[1]);
            pt[2] = fmaf(w0v[r], hyy, pt[2]);
            pt[3] = fmaf(w0v[r], hzz, pt[3]);
            pt[4] = fmaf(w1v[r], hv, pt[4]);
            pt[5] = fmaf(w1v[r], hxx, pt[5]);
            pt[6] = fmaf(w1v[r], hyy, pt[6]);
            pt[7] = fmaf(w1v[r], hzz, pt[7]);
        }
    }
    #pragma unroll
    for (int k = 0; k < 8; ++k) {
        pt[k] += __shfl_xor(pt[k], 16, 64);
        pt[k] += __shfl_xor(pt[k], 32, 64);
    }
    if (qc == 0) {
        *(float4*)&red[w][n15][0] = make_float4(pt[0], pt[1], pt[2], pt[3]);
        *(float4*)&red[w][n15][4] = make_float4(pt[4], pt[5], pt[6], pt[7]);
    }
    __syncthreads();

    if (tid < 16 && (pbase + tid) < N) {
        const int n = pbase + tid;
        float s8[8] = {0.f, 0.f, 0.f, 0.f, 0.f, 0.f, 0.f, 0.f};
        #pragma unroll
        for (int ww = 0; ww < 8; ++ww)
            #pragma unroll
            for (int k = 0; k < 8; ++k) s8[k] += red[ww][tid][k];
        const float fi = gf[n];
        const float PI = 3.14159265358979323846f;
        const float kw = 2.f * PI * (fi * 500.f + 100.f) / 343.f;
        const float vol = 0.7f * 0.5f * 0.6f;
        const float kk = vol * vol * kw * kw;
        const float cxx = (0.5f * 0.6f) * (0.5f * 0.6f);
        const float cyy = (0.7f * 0.6f) * (0.7f * 0.6f);
        const float czz = (0.7f * 0.5f) * (0.7f * 0.5f);
        const float pr = s8[0] + b4[0];
        const float pim = s8[4] + b4[1];
        out[n]     = 2.0f * (cxx * s8[1] + cyy * s8[2] + czz * s8[3]) + kk * (pr * 2.0f + 0.1f);
        out[N + n] = 1.5f * (cxx * s8[5] + cyy * s8[6] + czz * s8[7]) + kk * (pim * 1.5f - 0.05f);
    }
}

extern "C" void kernel_launch(void* const* d_in, const int* in_sizes, int n_in,
                              void* d_out, int out_size, void* d_ws, size_t ws_size,
                              hipStream_t stream) {
    const float* x = (const float*)d_in[0];
    const float* y = (const float*)d_in[1];
    const float* z = (const float*)d_in[2];
    const float* f = (const float*)d_in[3];
    const float* W1 = (const float*)d_in[4];
    const float* b1 = (const float*)d_in[5];
    const float* W2 = (const float*)d_in[6];
    const float* b2 = (const float*)d_in[7];
    const float* W3 = (const float*)d_in[8];
    const float* b3 = (const float*)d_in[9];
    const float* W4 = (const float*)d_in[10];
    const float* b4 = (const float*)d_in[11];
    float* out = (float*)d_out;
    const int N = in_sizes[0];
    const int grid = (N + PBLK - 1) / PBLK;

    prep_split<<<64, 256, 0, stream>>>(W2, W3, (short8*)d_ws);
    bvp_main<<<grid, 512, 0, stream>>>(x, y, z, f, W1, b1, b2, b3, W4, b4,
                                       (const short8*)d_ws, out, N);
}